// Round 2
// baseline (636.015 us; speedup 1.0000x reference)
//
#include <hip/hip_runtime.h>
#include <hip/hip_bf16.h>
#include <cstddef>

#define DMODEL 1024
#define DK 64
#define S1 2048
#define S2 1024
#define NBATCH 2

typedef __bf16 bf16x8 __attribute__((ext_vector_type(8)));
typedef float f32x4 __attribute__((ext_vector_type(4)));
typedef unsigned short u16x8 __attribute__((ext_vector_type(8)));
typedef unsigned int u32x4 __attribute__((ext_vector_type(4)));

__device__ __forceinline__ unsigned short f2bf(float f) {
  unsigned u = __builtin_bit_cast(unsigned, f);
  u = (u + 0x7FFFu + ((u >> 16) & 1u)) >> 16;
  return (unsigned short)u;
}

__device__ __forceinline__ bf16x8 ld_bf16x8(const unsigned short* p) {
  u32x4 v = *reinterpret_cast<const u32x4*>(p);
  return __builtin_bit_cast(bf16x8, v);
}

// ---- weight transpose: W[k][n] f32 -> Wt[n][k] bf16 ----
__global__ __launch_bounds__(1024) void transpose_w_kernel(
    const float* __restrict__ W, unsigned short* __restrict__ Wt) {
  __shared__ float t[32][33];
  int tx = threadIdx.x, ty = threadIdx.y;
  int n = blockIdx.x * 32 + tx;
  int k = blockIdx.y * 32 + ty;
  t[ty][tx] = W[(size_t)k * DMODEL + n];
  __syncthreads();
  int n2 = blockIdx.x * 32 + ty;
  int k2 = blockIdx.y * 32 + tx;
  Wt[(size_t)n2 * DMODEL + k2] = f2bf(t[tx][ty]);
}

// ---- GEMM: A[M][1024] f32 row-major  x  Bt[1024][1024] bf16 (B transposed) + bias
// MODE 0: plain f32 out [M][1024]
// MODE 1: Q/K projection scatter: heads 0-7 -> out1 [2,8,2048,64] bf16;
//         heads 8-15, even s -> out2 [2,8,1024,64] bf16
// MODE 2: V projection scatter, transposed: out1 [2,8,64,2048], out2 [2,8,64,1024]
template <int MODE>
__global__ __launch_bounds__(256) void gemm_bt(
    const float* __restrict__ A, const unsigned short* __restrict__ Bt,
    const float* __restrict__ bias, float* __restrict__ outF,
    unsigned short* __restrict__ out1, unsigned short* __restrict__ out2) {
  const int K = DMODEL;
  int w = threadIdx.x >> 6, lane = threadIdx.x & 63;
  int lo = lane & 15, hi = lane >> 4;
  int rowBase = blockIdx.y * 64 + w * 16;
  int colBase = blockIdx.x * 64;

  f32x4 acc[4] = {};
  const float* pa_row = A + (size_t)(rowBase + lo) * K + hi * 8;

  for (int k0 = 0; k0 < K; k0 += 32) {
    f32x4 a0 = *reinterpret_cast<const f32x4*>(pa_row + k0);
    f32x4 a1 = *reinterpret_cast<const f32x4*>(pa_row + k0 + 4);
    u16x8 ab;
#pragma unroll
    for (int j = 0; j < 4; ++j) {
      ab[j] = f2bf(a0[j]);
      ab[4 + j] = f2bf(a1[j]);
    }
    bf16x8 a = __builtin_bit_cast(bf16x8, ab);
#pragma unroll
    for (int nb = 0; nb < 4; ++nb) {
      bf16x8 b = ld_bf16x8(Bt + (size_t)(colBase + nb * 16 + lo) * K + k0 + hi * 8);
      acc[nb] = __builtin_amdgcn_mfma_f32_16x16x32_bf16(a, b, acc[nb], 0, 0, 0);
    }
  }

#pragma unroll
  for (int nb = 0; nb < 4; ++nb) {
    int col = colBase + nb * 16 + lo;
    float bv = bias[col];
#pragma unroll
    for (int r = 0; r < 4; ++r) {
      int row = rowBase + hi * 4 + r;
      float v = acc[nb][r] + bv;
      if (MODE == 0) {
        outF[(size_t)row * DMODEL + col] = v;
      } else {
        int b = row >> 11, s = row & 2047;
        int h = col >> 6, d = col & 63;
        if (MODE == 1) {
          if (h < 8)
            out1[(((size_t)(b * 8 + h)) * S1 + s) * DK + d] = f2bf(v);
          else if (!(s & 1))
            out2[(((size_t)(b * 8 + (h - 8))) * S2 + (s >> 1)) * DK + d] = f2bf(v);
        } else {
          if (h < 8)
            out1[(((size_t)(b * 8 + h)) * DK + d) * S1 + s] = f2bf(v);
          else if (!(s & 1))
            out2[(((size_t)(b * 8 + (h - 8))) * DK + d) * S2 + (s >> 1)] = f2bf(v);
        }
      }
    }
  }
}

// ---- flash attention: Q[16,Sq,64] bf16, K[16,Skv,64] bf16, Vt[16,64,Skv] bf16
// -> O[16,Sq,64] f32.  One wave per 16 q-rows, kv tiles of 32.
__global__ __launch_bounds__(256) void attn_kernel(
    const unsigned short* __restrict__ Q, const unsigned short* __restrict__ K,
    const unsigned short* __restrict__ Vt, float* __restrict__ O, int Sq, int Skv) {
  __shared__ unsigned short P_lds[4][16][32];
  int w = threadIdx.x >> 6, lane = threadIdx.x & 63;
  int lo = lane & 15, hi = lane >> 4;
  int bh = blockIdx.y;
  int q0 = blockIdx.x * 64 + w * 16;

  const unsigned short* Qp = Q + ((size_t)bh * Sq + q0) * DK;
  bf16x8 qa0 = ld_bf16x8(Qp + lo * DK + hi * 8);
  bf16x8 qa1 = ld_bf16x8(Qp + lo * DK + 32 + hi * 8);

  float mrow[4], lrow[4];
  f32x4 oacc[4] = {};
#pragma unroll
  for (int r = 0; r < 4; ++r) {
    mrow[r] = -1e30f;
    lrow[r] = 0.f;
  }

  const unsigned short* Kb = K + (size_t)bh * Skv * DK;
  const unsigned short* Vb = Vt + (size_t)bh * DK * Skv;

  for (int kv0 = 0; kv0 < Skv; kv0 += 32) {
    f32x4 s0 = {}, s1 = {};
    {
      bf16x8 kb0 = ld_bf16x8(Kb + (size_t)(kv0 + lo) * DK + hi * 8);
      s0 = __builtin_amdgcn_mfma_f32_16x16x32_bf16(qa0, kb0, s0, 0, 0, 0);
      bf16x8 kb1 = ld_bf16x8(Kb + (size_t)(kv0 + lo) * DK + 32 + hi * 8);
      s0 = __builtin_amdgcn_mfma_f32_16x16x32_bf16(qa1, kb1, s0, 0, 0, 0);
      bf16x8 kb2 = ld_bf16x8(Kb + (size_t)(kv0 + 16 + lo) * DK + hi * 8);
      s1 = __builtin_amdgcn_mfma_f32_16x16x32_bf16(qa0, kb2, s1, 0, 0, 0);
      bf16x8 kb3 = ld_bf16x8(Kb + (size_t)(kv0 + 16 + lo) * DK + 32 + hi * 8);
      s1 = __builtin_amdgcn_mfma_f32_16x16x32_bf16(qa1, kb3, s1, 0, 0, 0);
    }
    float alpha[4];
#pragma unroll
    for (int r = 0; r < 4; ++r) {
      float x0 = s0[r] * 0.125f, x1 = s1[r] * 0.125f;
      float mx = fmaxf(x0, x1);
      mx = fmaxf(mx, __shfl_xor(mx, 1));
      mx = fmaxf(mx, __shfl_xor(mx, 2));
      mx = fmaxf(mx, __shfl_xor(mx, 4));
      mx = fmaxf(mx, __shfl_xor(mx, 8));
      float mn = fmaxf(mrow[r], mx);
      float al = __expf(mrow[r] - mn);
      mrow[r] = mn;
      float p0 = __expf(x0 - mn), p1 = __expf(x1 - mn);
      float rs = p0 + p1;
      rs += __shfl_xor(rs, 1);
      rs += __shfl_xor(rs, 2);
      rs += __shfl_xor(rs, 4);
      rs += __shfl_xor(rs, 8);
      lrow[r] = lrow[r] * al + rs;
      alpha[r] = al;
      P_lds[w][hi * 4 + r][lo] = f2bf(p0);
      P_lds[w][hi * 4 + r][16 + lo] = f2bf(p1);
    }
#pragma unroll
    for (int nb = 0; nb < 4; ++nb) {
      f32x4 t = oacc[nb];
      t[0] *= alpha[0];
      t[1] *= alpha[1];
      t[2] *= alpha[2];
      t[3] *= alpha[3];
      oacc[nb] = t;
    }
    bf16x8 pa = ld_bf16x8(&P_lds[w][lo][hi * 8]);
#pragma unroll
    for (int nb = 0; nb < 4; ++nb) {
      bf16x8 vb = ld_bf16x8(Vb + (size_t)(nb * 16 + lo) * Skv + kv0 + hi * 8);
      oacc[nb] = __builtin_amdgcn_mfma_f32_16x16x32_bf16(pa, vb, oacc[nb], 0, 0, 0);
    }
  }

  float* Op = O + ((size_t)bh * Sq + q0) * DK;
#pragma unroll
  for (int nb = 0; nb < 4; ++nb) {
#pragma unroll
    for (int r = 0; r < 4; ++r) {
      Op[(size_t)(hi * 4 + r) * DK + nb * 16 + lo] = oacc[nb][r] / lrow[r];
    }
  }
}

// ---- build ctx f32 [2,2048,1024]: heads 0-7 from O1, heads 8-15 upsampled from O2
__global__ __launch_bounds__(256) void build_ctx_kernel(
    const float* __restrict__ O1, const float* __restrict__ O2,
    float* __restrict__ ctx) {
  int c = blockIdx.x * 256 + threadIdx.x;
  if (c >= NBATCH * S1 * DMODEL) return;
  int col = c & (DMODEL - 1);
  int m_ = c >> 10;
  int s = m_ & (S1 - 1);
  int b = m_ >> 11;
  int h = col >> 6, d = col & 63;
  float v;
  if (h < 8) {
    v = O1[(((size_t)(b * 8 + h)) * S1 + s) * DK + d];
  } else {
    const float* X = O2 + ((size_t)(b * 8 + (h - 8))) * S2 * DK + d;
    int mm = s >> 1;
    if (s & 1) {
      int i1 = (mm + 1 < S2) ? mm + 1 : S2 - 1;
      v = 0.75f * X[(size_t)mm * DK] + 0.25f * X[(size_t)i1 * DK];
    } else {
      v = (mm == 0) ? X[0]
                    : (0.25f * X[(size_t)(mm - 1) * DK] + 0.75f * X[(size_t)mm * DK]);
    }
  }
  ctx[c] = v;
}

extern "C" void kernel_launch(void* const* d_in, const int* in_sizes, int n_in,
                              void* d_out, int out_size, void* d_ws, size_t ws_size,
                              hipStream_t stream) {
  const float* query = (const float*)d_in[0];
  const float* key = (const float*)d_in[1];
  const float* value = (const float*)d_in[2];
  const float* w_q = (const float*)d_in[3];
  const float* b_q = (const float*)d_in[4];
  const float* w_k = (const float*)d_in[5];
  const float* b_k = (const float*)d_in[6];
  const float* w_v = (const float*)d_in[7];
  const float* b_v = (const float*)d_in[8];
  const float* w_o = (const float*)d_in[9];
  const float* b_o = (const float*)d_in[10];
  float* out = (float*)d_out;

  char* ws = (char*)d_ws;
  size_t off = 0;
  auto alloc = [&](size_t bytes) {
    char* p = ws + off;
    off += (bytes + 255) & ~(size_t)255;
    return p;
  };
  const size_t WT_B = (size_t)DMODEL * DMODEL * 2;
  unsigned short* WqT = (unsigned short*)alloc(WT_B);
  unsigned short* WkT = (unsigned short*)alloc(WT_B);
  unsigned short* WvT = (unsigned short*)alloc(WT_B);
  unsigned short* WoT = (unsigned short*)alloc(WT_B);
  unsigned short* Q1 = (unsigned short*)alloc((size_t)16 * S1 * DK * 2);
  unsigned short* K1 = (unsigned short*)alloc((size_t)16 * S1 * DK * 2);
  unsigned short* V1t = (unsigned short*)alloc((size_t)16 * S1 * DK * 2);
  unsigned short* Q2 = (unsigned short*)alloc((size_t)16 * S2 * DK * 2);
  unsigned short* K2 = (unsigned short*)alloc((size_t)16 * S2 * DK * 2);
  unsigned short* V2t = (unsigned short*)alloc((size_t)16 * S2 * DK * 2);
  float* O1 = (float*)alloc((size_t)16 * S1 * DK * 4);
  float* O2 = (float*)alloc((size_t)16 * S2 * DK * 4);
  float* ctx = (float*)alloc((size_t)NBATCH * S1 * DMODEL * 4);

  dim3 tb(32, 32), tg(32, 32);
  transpose_w_kernel<<<tg, tb, 0, stream>>>(w_q, WqT);
  transpose_w_kernel<<<tg, tb, 0, stream>>>(w_k, WkT);
  transpose_w_kernel<<<tg, tb, 0, stream>>>(w_v, WvT);
  transpose_w_kernel<<<tg, tb, 0, stream>>>(w_o, WoT);

  dim3 gg(DMODEL / 64, (NBATCH * S1) / 64);  // (16, 64)
  gemm_bt<1><<<gg, 256, 0, stream>>>(query, WqT, b_q, nullptr, Q1, Q2);
  gemm_bt<1><<<gg, 256, 0, stream>>>(key, WkT, b_k, nullptr, K1, K2);
  gemm_bt<2><<<gg, 256, 0, stream>>>(value, WvT, b_v, nullptr, V1t, V2t);

  attn_kernel<<<dim3(S1 / 64, 16), 256, 0, stream>>>(Q1, K1, V1t, O1, S1, S1);
  attn_kernel<<<dim3(S2 / 64, 16), 256, 0, stream>>>(Q2, K2, V2t, O2, S2, S2);

  build_ctx_kernel<<<(NBATCH * S1 * DMODEL) / 256, 256, 0, stream>>>(O1, O2, ctx);

  gemm_bt<0><<<gg, 256, 0, stream>>>(ctx, WoT, b_o, out, nullptr, nullptr);
}

// Round 3
// 576.052 us; speedup vs baseline: 1.1041x; 1.1041x over previous
//
#include <hip/hip_runtime.h>
#include <hip/hip_bf16.h>
#include <cstddef>

#define DMODEL 1024
#define DK 64
#define S1 2048
#define S2 1024
#define NBATCH 2

typedef __bf16 bf16x8 __attribute__((ext_vector_type(8)));
typedef float f32x4 __attribute__((ext_vector_type(4)));
typedef unsigned short u16x4 __attribute__((ext_vector_type(4)));
typedef unsigned int u32x4 __attribute__((ext_vector_type(4)));

__device__ __forceinline__ unsigned short f2bf(float f) {
  unsigned u = __builtin_bit_cast(unsigned, f);
  u = (u + 0x7FFFu + ((u >> 16) & 1u)) >> 16;
  return (unsigned short)u;
}
__device__ __forceinline__ float bf2f(unsigned short u) {
  unsigned x = ((unsigned)u) << 16;
  return __builtin_bit_cast(float, x);
}
__device__ __forceinline__ bf16x8 ld_bf16x8(const unsigned short* p) {
  u32x4 v = *reinterpret_cast<const u32x4*>(p);
  return __builtin_bit_cast(bf16x8, v);
}

// ---- f32 -> bf16 vectorized convert ----
__global__ __launch_bounds__(256) void cvt_bf16_kernel(
    const float* __restrict__ in, unsigned short* __restrict__ out, int n4) {
  int i = blockIdx.x * 256 + threadIdx.x;
  if (i >= n4) return;
  f32x4 v = reinterpret_cast<const f32x4*>(in)[i];
  u16x4 r;
#pragma unroll
  for (int j = 0; j < 4; ++j) r[j] = f2bf(v[j]);
  reinterpret_cast<u16x4*>(out)[i] = r;
}

// ---- weight transpose: W[k][n] f32 -> Wt[n][k] bf16 ----
__global__ __launch_bounds__(1024) void transpose_w_kernel(
    const float* __restrict__ W, unsigned short* __restrict__ Wt) {
  __shared__ float t[32][33];
  int tx = threadIdx.x, ty = threadIdx.y;
  int n = blockIdx.x * 32 + tx;
  int k = blockIdx.y * 32 + ty;
  t[ty][tx] = W[(size_t)k * DMODEL + n];
  __syncthreads();
  int n2 = blockIdx.x * 32 + ty;
  int k2 = blockIdx.y * 32 + tx;
  Wt[(size_t)n2 * DMODEL + k2] = f2bf(t[tx][ty]);
}

// ---- GEMM: A[M][1024] bf16 row-major x Bt[1024][1024] bf16 + bias
// MODE 0: f32 out [M][1024]
// MODE 1: Q/K scatter: heads 0-7 -> out1 [2,8,2048,64]; heads 8-15 even s -> out2 [2,8,1024,64]
// MODE 2: V scatter transposed: out1 [2,8,64,2048], out2 [2,8,64,1024]
template <int MODE>
__global__ __launch_bounds__(256) void gemm_bf16(
    const unsigned short* __restrict__ A, const unsigned short* __restrict__ Bt,
    const float* __restrict__ bias, float* __restrict__ outF,
    unsigned short* __restrict__ out1, unsigned short* __restrict__ out2) {
  int w = threadIdx.x >> 6, lane = threadIdx.x & 63;
  int lo = lane & 15, hi = lane >> 4;
  int rowBase = blockIdx.y * 64 + w * 16;
  int colBase = blockIdx.x * 64;

  f32x4 acc[4] = {};
  const unsigned short* pa = A + (size_t)(rowBase + lo) * DMODEL + hi * 8;
  const unsigned short* pb = Bt + (size_t)(colBase + lo) * DMODEL + hi * 8;

  for (int k0 = 0; k0 < DMODEL; k0 += 32) {
    bf16x8 a = ld_bf16x8(pa + k0);
#pragma unroll
    for (int nb = 0; nb < 4; ++nb) {
      bf16x8 b = ld_bf16x8(pb + (size_t)nb * 16 * DMODEL + k0);
      acc[nb] = __builtin_amdgcn_mfma_f32_16x16x32_bf16(a, b, acc[nb], 0, 0, 0);
    }
  }

#pragma unroll
  for (int nb = 0; nb < 4; ++nb) {
    int col = colBase + nb * 16 + lo;
    float bv = bias[col];
#pragma unroll
    for (int r = 0; r < 4; ++r) {
      int row = rowBase + hi * 4 + r;
      float v = acc[nb][r] + bv;
      if (MODE == 0) {
        outF[(size_t)row * DMODEL + col] = v;
      } else {
        int b = row >> 11, s = row & 2047;
        int h = col >> 6, d = col & 63;
        if (MODE == 1) {
          if (h < 8)
            out1[(((size_t)(b * 8 + h)) * S1 + s) * DK + d] = f2bf(v);
          else if (!(s & 1))
            out2[(((size_t)(b * 8 + (h - 8))) * S2 + (s >> 1)) * DK + d] = f2bf(v);
        } else {
          if (h < 8)
            out1[(((size_t)(b * 8 + h)) * DK + d) * S1 + s] = f2bf(v);
          else if (!(s & 1))
            out2[(((size_t)(b * 8 + (h - 8))) * DK + d) * S2 + (s >> 1)] = f2bf(v);
        }
      }
    }
  }
}

// ---- flash attention, swapped-QK^T softmax.
// Q[16,Sq,64], K[16,Skv,64], Vt[16,64,Skv] bf16.
// CTX=1: output bf16 into ctx[2,S1,1024] cols h*64.. (heads 0-7)
// CTX=0: output bf16 compact [16,Sq,64]
template <int CTX>
__global__ __launch_bounds__(256) void attn_kernel(
    const unsigned short* __restrict__ Q, const unsigned short* __restrict__ K,
    const unsigned short* __restrict__ Vt, unsigned short* __restrict__ O,
    int Sq, int Skv) {
  __shared__ unsigned short P_lds[4][16][32];
  int w = threadIdx.x >> 6, lane = threadIdx.x & 63;
  int lo = lane & 15, hi = lane >> 4;
  int bh = blockIdx.y;
  int q0 = blockIdx.x * 64 + w * 16;

  const unsigned short* Qp = Q + ((size_t)bh * Sq + q0) * DK;
  bf16x8 qb0 = ld_bf16x8(Qp + lo * DK + hi * 8);       // Q[q=lo][dk=hi*8+j]
  bf16x8 qb1 = ld_bf16x8(Qp + lo * DK + 32 + hi * 8);

  float m = -1e30f, l = 0.f;
  f32x4 oacc[4] = {};
  const unsigned short* Kb = K + (size_t)bh * Skv * DK;
  const unsigned short* Vb = Vt + (size_t)bh * DK * Skv;

  for (int kv0 = 0; kv0 < Skv; kv0 += 32) {
    // QK^T swapped: D[kv][q]; lane holds P[kv=hi*4+r (+16)][q=lo]
    f32x4 s0 = {}, s1 = {};
    {
      bf16x8 ka0 = ld_bf16x8(Kb + (size_t)(kv0 + lo) * DK + hi * 8);
      s0 = __builtin_amdgcn_mfma_f32_16x16x32_bf16(ka0, qb0, s0, 0, 0, 0);
      bf16x8 ka1 = ld_bf16x8(Kb + (size_t)(kv0 + lo) * DK + 32 + hi * 8);
      s0 = __builtin_amdgcn_mfma_f32_16x16x32_bf16(ka1, qb1, s0, 0, 0, 0);
      bf16x8 ka2 = ld_bf16x8(Kb + (size_t)(kv0 + 16 + lo) * DK + hi * 8);
      s1 = __builtin_amdgcn_mfma_f32_16x16x32_bf16(ka2, qb0, s1, 0, 0, 0);
      bf16x8 ka3 = ld_bf16x8(Kb + (size_t)(kv0 + 16 + lo) * DK + 32 + hi * 8);
      s1 = __builtin_amdgcn_mfma_f32_16x16x32_bf16(ka3, qb1, s1, 0, 0, 0);
    }
    float x[8];
#pragma unroll
    for (int r = 0; r < 4; ++r) {
      x[r] = s0[r] * 0.125f;
      x[4 + r] = s1[r] * 0.125f;
    }
    float tmax = x[0];
#pragma unroll
    for (int j = 1; j < 8; ++j) tmax = fmaxf(tmax, x[j]);
    tmax = fmaxf(tmax, __shfl_xor(tmax, 16));
    tmax = fmaxf(tmax, __shfl_xor(tmax, 32));
    float mnew = fmaxf(m, tmax);
    float alpha = __expf(m - mnew);
    m = mnew;
    float p[8], tsum = 0.f;
#pragma unroll
    for (int j = 0; j < 8; ++j) {
      p[j] = __expf(x[j] - mnew);
      tsum += p[j];
    }
    tsum += __shfl_xor(tsum, 16);
    tsum += __shfl_xor(tsum, 32);
    l = l * alpha + tsum;

    // transpose P via LDS: write [q=lo][kv] packed pairs
    unsigned pk0 = (unsigned)f2bf(p[0]) | ((unsigned)f2bf(p[1]) << 16);
    unsigned pk1 = (unsigned)f2bf(p[2]) | ((unsigned)f2bf(p[3]) << 16);
    unsigned pk2 = (unsigned)f2bf(p[4]) | ((unsigned)f2bf(p[5]) << 16);
    unsigned pk3 = (unsigned)f2bf(p[6]) | ((unsigned)f2bf(p[7]) << 16);
    unsigned* prow = reinterpret_cast<unsigned*>(&P_lds[w][lo][0]);
    prow[2 * hi] = pk0;
    prow[2 * hi + 1] = pk1;
    prow[8 + 2 * hi] = pk2;
    prow[8 + 2 * hi + 1] = pk3;

    // broadcast alpha to accumulator rows (q = hi*4+r)
    float ar[4];
#pragma unroll
    for (int r = 0; r < 4; ++r) ar[r] = __shfl(alpha, hi * 4 + r);
#pragma unroll
    for (int nb = 0; nb < 4; ++nb) {
      f32x4 t = oacc[nb];
      t[0] *= ar[0];
      t[1] *= ar[1];
      t[2] *= ar[2];
      t[3] *= ar[3];
      oacc[nb] = t;
    }
    bf16x8 pa = ld_bf16x8(&P_lds[w][lo][hi * 8]);
#pragma unroll
    for (int nb = 0; nb < 4; ++nb) {
      bf16x8 vb = ld_bf16x8(Vb + (size_t)(nb * 16 + lo) * Skv + kv0 + hi * 8);
      oacc[nb] = __builtin_amdgcn_mfma_f32_16x16x32_bf16(pa, vb, oacc[nb], 0, 0, 0);
    }
  }

  float li[4];
#pragma unroll
  for (int r = 0; r < 4; ++r) li[r] = 1.0f / __shfl(l, hi * 4 + r);

  unsigned short* Op;
  int strideRow;
  if (CTX) {
    int b = bh >> 3, h = bh & 7;
    Op = O + ((size_t)(b * S1 + q0)) * DMODEL + h * 64;
    strideRow = DMODEL;
  } else {
    Op = O + ((size_t)bh * Sq + q0) * DK;
    strideRow = DK;
  }
#pragma unroll
  for (int nb = 0; nb < 4; ++nb)
#pragma unroll
    for (int r = 0; r < 4; ++r)
      Op[(size_t)(hi * 4 + r) * strideRow + nb * 16 + lo] =
          f2bf(oacc[nb][r] * li[r]);
}

// ---- upsample heads 8-15 from O2 bf16 [2,8,1024,64] into ctx cols 512-1023
__global__ __launch_bounds__(256) void upsample_kernel(
    const unsigned short* __restrict__ O2, unsigned short* __restrict__ ctx) {
  int c = blockIdx.x * 256 + threadIdx.x;
  if (c >= NBATCH * S1 * 512) return;
  int col = c & 511;
  int m_ = c >> 9;
  int s = m_ & (S1 - 1);
  int b = m_ >> 11;
  int h = col >> 6, d = col & 63;
  const unsigned short* X = O2 + ((size_t)(b * 8 + h)) * S2 * DK + d;
  int mm = s >> 1;
  float v;
  if (s & 1) {
    int i1 = (mm + 1 < S2) ? mm + 1 : S2 - 1;
    v = 0.75f * bf2f(X[(size_t)mm * DK]) + 0.25f * bf2f(X[(size_t)i1 * DK]);
  } else {
    v = (mm == 0) ? bf2f(X[0])
                  : (0.25f * bf2f(X[(size_t)(mm - 1) * DK]) +
                     0.75f * bf2f(X[(size_t)mm * DK]));
  }
  ctx[((size_t)(b * S1 + s)) * DMODEL + 512 + col] = f2bf(v);
}

extern "C" void kernel_launch(void* const* d_in, const int* in_sizes, int n_in,
                              void* d_out, int out_size, void* d_ws, size_t ws_size,
                              hipStream_t stream) {
  const float* query = (const float*)d_in[0];
  const float* key = (const float*)d_in[1];
  const float* value = (const float*)d_in[2];
  const float* w_q = (const float*)d_in[3];
  const float* b_q = (const float*)d_in[4];
  const float* w_k = (const float*)d_in[5];
  const float* b_k = (const float*)d_in[6];
  const float* w_v = (const float*)d_in[7];
  const float* b_v = (const float*)d_in[8];
  const float* w_o = (const float*)d_in[9];
  const float* b_o = (const float*)d_in[10];
  float* out = (float*)d_out;

  char* ws = (char*)d_ws;
  size_t off = 0;
  auto alloc = [&](size_t bytes) {
    char* p = ws + off;
    off += (bytes + 255) & ~(size_t)255;
    return p;
  };
  const size_t WT_B = (size_t)DMODEL * DMODEL * 2;
  unsigned short* WqT = (unsigned short*)alloc(WT_B);
  unsigned short* WkT = (unsigned short*)alloc(WT_B);
  unsigned short* WvT = (unsigned short*)alloc(WT_B);
  unsigned short* WoT = (unsigned short*)alloc(WT_B);
  unsigned short* xk = (unsigned short*)alloc((size_t)NBATCH * S1 * DMODEL * 2);
  unsigned short* xv = (unsigned short*)alloc((size_t)NBATCH * S1 * DMODEL * 2);
  unsigned short* Q1 = (unsigned short*)alloc((size_t)16 * S1 * DK * 2);
  unsigned short* K1 = (unsigned short*)alloc((size_t)16 * S1 * DK * 2);
  unsigned short* V1t = (unsigned short*)alloc((size_t)16 * S1 * DK * 2);
  unsigned short* Q2 = (unsigned short*)alloc((size_t)16 * S2 * DK * 2);
  unsigned short* K2 = (unsigned short*)alloc((size_t)16 * S2 * DK * 2);
  unsigned short* V2t = (unsigned short*)alloc((size_t)16 * S2 * DK * 2);
  unsigned short* O2 = (unsigned short*)alloc((size_t)16 * S2 * DK * 2);
  unsigned short* ctx = (unsigned short*)alloc((size_t)NBATCH * S1 * DMODEL * 2);
  unsigned short* xq = ctx;  // aliased: xq consumed before ctx is written

  const int n4 = NBATCH * S1 * DMODEL / 4;
  cvt_bf16_kernel<<<n4 / 256, 256, 0, stream>>>(query, xq, n4);
  cvt_bf16_kernel<<<n4 / 256, 256, 0, stream>>>(key, xk, n4);
  cvt_bf16_kernel<<<n4 / 256, 256, 0, stream>>>(value, xv, n4);

  dim3 tb(32, 32), tg(32, 32);
  transpose_w_kernel<<<tg, tb, 0, stream>>>(w_q, WqT);
  transpose_w_kernel<<<tg, tb, 0, stream>>>(w_k, WkT);
  transpose_w_kernel<<<tg, tb, 0, stream>>>(w_v, WvT);
  transpose_w_kernel<<<tg, tb, 0, stream>>>(w_o, WoT);

  dim3 gg(DMODEL / 64, (NBATCH * S1) / 64);  // (16, 64)
  gemm_bf16<1><<<gg, 256, 0, stream>>>(xq, WqT, b_q, nullptr, Q1, Q2);
  gemm_bf16<1><<<gg, 256, 0, stream>>>(xk, WkT, b_k, nullptr, K1, K2);
  gemm_bf16<2><<<gg, 256, 0, stream>>>(xv, WvT, b_v, nullptr, V1t, V2t);

  attn_kernel<1><<<dim3(S1 / 64, 16), 256, 0, stream>>>(Q1, K1, V1t, ctx, S1, S1);
  attn_kernel<0><<<dim3(S2 / 64, 16), 256, 0, stream>>>(Q2, K2, V2t, O2, S2, S2);

  upsample_kernel<<<(NBATCH * S1 * 512) / 256, 256, 0, stream>>>(O2, ctx);

  gemm_bf16<0><<<gg, 256, 0, stream>>>(ctx, WoT, b_o, out, nullptr, nullptr);
}